// Round 10
// baseline (28.921 us; speedup 1.0000x reference)
//
#include <hip/hip_runtime.h>
#include <math.h>

typedef unsigned short u16;
typedef unsigned int   u32;
typedef u16 us2 __attribute__((ext_vector_type(2)));

constexpr int BB = 2, CC = 4, DD = 64, HH = 64, WW = 64;
constexpr int HW   = HH * WW;      // 4096
constexpr int DHW  = DD * HW;      // 262144
constexpr int CDHW = CC * DHW;     // 1048576
constexpr int NTOT = BB * CDHW;    // 2097152
constexpr int NBLK = 512;
constexpr u32 SENT = 50000;        // u16 "infinity": 50000+3969+3969 < 65536 (SWAR-safe)

__device__ __forceinline__ u32 pkmin(u32 a, u32 b) {
    us2 r = __builtin_elementwise_min(__builtin_bit_cast(us2, a),
                                      __builtin_bit_cast(us2, b));
    return __builtin_bit_cast(u32, r);
}

// ---------------------------------------------------------------------------
// Kernel A: block = (b,c,d), 256 threads.
//  (1) W-pass: 4 waves x 16 rows, ballot nearest-set-bit -> u16 LDS.
//  (2) H-pass: packed-u16 min-plus, 2 i-rows x 8 w per thread (each
//      ds_read_b128 feeds 2 rows -> half the LDS instructions of R9).
//  (3) softmax probs for h-quarter [16c,16c+16) -> probT (f32).
// ---------------------------------------------------------------------------
__global__ __launch_bounds__(256) void edt_wh_prob(const int* __restrict__ tgt,
                                                   const float* __restrict__ pred,
                                                   u16* __restrict__ dsqT,
                                                   float* __restrict__ probT) {
    __shared__ u16 fs[HW];   // 8 KB W-pass result [h][w]
    const int t    = threadIdx.x;
    const int blk  = blockIdx.x;
    const int lane = t & 63;
    const int wv   = t >> 6;           // 4 waves
    const int b = blk >> 8;
    const int c = (blk >> 6) & 3;
    const int d = blk & 63;
    const size_t tb = (size_t)(b * 64 + d) * HW;   // tgt[b][d][:][:]

    // W-pass: 16 rows per wave.
    #pragma unroll
    for (int r = 0; r < 16; ++r) {
        const int h   = wv * 16 + r;
        const int cls = tgt[tb + h * 64 + lane];
        const unsigned long long mask = __ballot(cls == c);
        const unsigned long long mlo  = mask & (~0ull >> (63 - lane));
        const unsigned long long mhi  = mask & (~0ull << lane);
        int dd = 1000;
        if (mlo) dd = lane - (63 - __builtin_clzll(mlo));
        if (mhi) dd = min(dd, (int)__builtin_ctzll(mhi) - lane);
        fs[h * 64 + lane] = (dd >= 1000) ? (u16)SENT : (u16)(dd * dd);
    }
    __syncthreads();

    // H-pass: 2 output rows (i0, i0+1) x 8 w per thread, packed u16.
    const int i0 = (t >> 3) * 2;    // 0,2,..,62
    const int wg = (t & 7) * 8;     // 8 consecutive w
    u32 a00 = 0xFFFFFFFFu, a01 = 0xFFFFFFFFu, a02 = 0xFFFFFFFFu, a03 = 0xFFFFFFFFu;
    u32 a10 = 0xFFFFFFFFu, a11 = 0xFFFFFFFFu, a12 = 0xFFFFFFFFu, a13 = 0xFFFFFFFFu;
    #pragma unroll 8
    for (int j = 0; j < 64; ++j) {
        const uint4 v = *reinterpret_cast<const uint4*>(&fs[j * 64 + wg]);
        const int  d0 = i0 - j, d1 = i0 + 1 - j;
        const u32  c0 = (u32)(d0 * d0) * 0x00010001u;
        const u32  c1 = (u32)(d1 * d1) * 0x00010001u;
        a00 = pkmin(a00, v.x + c0);  a10 = pkmin(a10, v.x + c1);
        a01 = pkmin(a01, v.y + c0);  a11 = pkmin(a11, v.y + c1);
        a02 = pkmin(a02, v.z + c0);  a12 = pkmin(a12, v.z + c1);
        a03 = pkmin(a03, v.w + c0);  a13 = pkmin(a13, v.w + c1);
    }
    const size_t ob0 = ((size_t)(b * 4 + c) * 64 + i0) * HW + d * 64 + wg;
    *reinterpret_cast<uint4*>(&dsqT[ob0])      = make_uint4(a00, a01, a02, a03);
    *reinterpret_cast<uint4*>(&dsqT[ob0 + HW]) = make_uint4(a10, a11, a12, a13);

    // Softmax probs: quarter rows [16c,16c+16), one float4 per thread.
    {
        const int hh = c * 16 + (t >> 4);
        const int w0 = (t & 15) * 4;
        const size_t pidx = (size_t)b * CDHW + (size_t)d * HW + (size_t)hh * 64 + w0;
        const float4 q0 = *reinterpret_cast<const float4*>(&pred[pidx]);
        const float4 q1 = *reinterpret_cast<const float4*>(&pred[pidx + (size_t)DHW]);
        const float4 q2 = *reinterpret_cast<const float4*>(&pred[pidx + 2 * (size_t)DHW]);
        const float4 q3 = *reinterpret_cast<const float4*>(&pred[pidx + 3 * (size_t)DHW]);
        float4 o0, o1, o2, o3;
        #define SMAX(X)                                                          \
        {   const float m = fmaxf(fmaxf(q0.X, q1.X), fmaxf(q2.X, q3.X));         \
            const float e0 = __expf(q0.X - m), e1 = __expf(q1.X - m),            \
                        e2 = __expf(q2.X - m), e3 = __expf(q3.X - m);            \
            const float zinv = 1.0f / (e0 + e1 + e2 + e3);                       \
            o0.X = e0 * zinv; o1.X = e1 * zinv;                                  \
            o2.X = e2 * zinv; o3.X = e3 * zinv; }
        SMAX(x) SMAX(y) SMAX(z) SMAX(w)
        #undef SMAX
        const size_t ob = (size_t)b * CDHW + (size_t)hh * HW + d * 64 + w0;
        *reinterpret_cast<float4*>(&probT[ob])                   = o0;
        *reinterpret_cast<float4*>(&probT[ob + (size_t)DHW])     = o1;
        *reinterpret_cast<float4*>(&probT[ob + 2 * (size_t)DHW]) = o2;
        *reinterpret_cast<float4*>(&probT[ob + 3 * (size_t)DHW]) = o3;
    }
}

// ---------------------------------------------------------------------------
// Kernel B: block = (b,c,h) = blk, 256 threads. Stages the contiguous 8 KB
// u16 dsq slab, packed min-plus along d with a 2-row register tile, direct
// prob reads (64 B/thread), fused prob*sqrt reduce (16 pts/thread), partial.
// ---------------------------------------------------------------------------
__global__ __launch_bounds__(256) void edt_d_reduce(const u16* __restrict__ dsqT,
                                                    const float* __restrict__ probT,
                                                    float* __restrict__ partial) {
    __shared__ u16   sdq[HW];   // 8 KB slab [d][w]
    __shared__ float wsum[4];
    const int t   = threadIdx.x;
    const int blk = blockIdx.x;
    const size_t base = (size_t)blk * HW;   // u16 units (and float units for probT)

    // Stage 8 KB: two uint4 per thread, fully coalesced.
    {
        const uint4 s0 = reinterpret_cast<const uint4*>(&dsqT[base])[t];
        const uint4 s1 = reinterpret_cast<const uint4*>(&dsqT[base])[t + 256];
        reinterpret_cast<uint4*>(sdq)[t]       = s0;
        reinterpret_cast<uint4*>(sdq)[t + 256] = s1;
    }
    __syncthreads();

    const int i0 = (t >> 3) * 2;    // output d-rows i0, i0+1
    const int wg = (t & 7) * 8;
    u32 a00 = 0xFFFFFFFFu, a01 = 0xFFFFFFFFu, a02 = 0xFFFFFFFFu, a03 = 0xFFFFFFFFu;
    u32 a10 = 0xFFFFFFFFu, a11 = 0xFFFFFFFFu, a12 = 0xFFFFFFFFu, a13 = 0xFFFFFFFFu;
    #pragma unroll 8
    for (int j = 0; j < 64; ++j) {
        const uint4 v = *reinterpret_cast<const uint4*>(&sdq[j * 64 + wg]);
        const int  d0 = i0 - j, d1 = i0 + 1 - j;
        const u32  c0 = (u32)(d0 * d0) * 0x00010001u;
        const u32  c1 = (u32)(d1 * d1) * 0x00010001u;
        a00 = pkmin(a00, v.x + c0);  a10 = pkmin(a10, v.x + c1);
        a01 = pkmin(a01, v.y + c0);  a11 = pkmin(a11, v.y + c1);
        a02 = pkmin(a02, v.z + c0);  a12 = pkmin(a12, v.z + c1);
        a03 = pkmin(a03, v.w + c0);  a13 = pkmin(a13, v.w + c1);
    }

    // Fused reduce: prob[b][c][h][i][w] * sqrt(dsq), 16 points per thread.
    const float4 p00 = *reinterpret_cast<const float4*>(&probT[base + i0 * 64 + wg]);
    const float4 p01 = *reinterpret_cast<const float4*>(&probT[base + i0 * 64 + wg + 4]);
    const float4 p10 = *reinterpret_cast<const float4*>(&probT[base + (i0 + 1) * 64 + wg]);
    const float4 p11 = *reinterpret_cast<const float4*>(&probT[base + (i0 + 1) * 64 + wg + 4]);
    float vsum =
        p00.x * sqrtf((float)(a00 & 0xFFFFu)) + p00.y * sqrtf((float)(a00 >> 16)) +
        p00.z * sqrtf((float)(a01 & 0xFFFFu)) + p00.w * sqrtf((float)(a01 >> 16)) +
        p01.x * sqrtf((float)(a02 & 0xFFFFu)) + p01.y * sqrtf((float)(a02 >> 16)) +
        p01.z * sqrtf((float)(a03 & 0xFFFFu)) + p01.w * sqrtf((float)(a03 >> 16)) +
        p10.x * sqrtf((float)(a10 & 0xFFFFu)) + p10.y * sqrtf((float)(a10 >> 16)) +
        p10.z * sqrtf((float)(a11 & 0xFFFFu)) + p10.w * sqrtf((float)(a11 >> 16)) +
        p11.x * sqrtf((float)(a12 & 0xFFFFu)) + p11.y * sqrtf((float)(a12 >> 16)) +
        p11.z * sqrtf((float)(a13 & 0xFFFFu)) + p11.w * sqrtf((float)(a13 >> 16));

    const int lane = t & 63;
    #pragma unroll
    for (int off = 32; off > 0; off >>= 1) vsum += __shfl_down(vsum, off, 64);
    if (lane == 0) wsum[t >> 6] = vsum;
    __syncthreads();
    if (t == 0) partial[blk] = wsum[0] + wsum[1] + wsum[2] + wsum[3];
}

// ---------------------------------------------------------------------------
// Kernel C: single-block deterministic final sum.
// ---------------------------------------------------------------------------
__global__ __launch_bounds__(256) void bl_final(const float* __restrict__ partial,
                                                float* __restrict__ out) {
    __shared__ double sd[256];
    double s = (double)partial[threadIdx.x] + (double)partial[threadIdx.x + 256];
    sd[threadIdx.x] = s;
    __syncthreads();
    for (int str = 128; str > 0; str >>= 1) {
        if (threadIdx.x < str) sd[threadIdx.x] += sd[threadIdx.x + str];
        __syncthreads();
    }
    if (threadIdx.x == 0) out[0] = (float)(sd[0] / (double)NTOT);
}

// ---------------------------------------------------------------------------
extern "C" void kernel_launch(void* const* d_in, const int* in_sizes, int n_in,
                              void* d_out, int out_size, void* d_ws, size_t ws_size,
                              hipStream_t stream) {
    const float* pred = (const float*)d_in[0];
    const int*   tgt  = (const int*)d_in[1];
    float* out     = (float*)d_out;
    u16*   dsqT    = (u16*)d_ws;                         // NTOT u16 (4 MB)
    float* probT   = (float*)((char*)d_ws + (size_t)NTOT * sizeof(u16));  // 8 MB
    float* partial = probT + NTOT;                       // NBLK floats

    hipLaunchKernelGGL(edt_wh_prob,  dim3(NBLK), dim3(256), 0, stream,
                       tgt, pred, dsqT, probT);
    hipLaunchKernelGGL(edt_d_reduce, dim3(NBLK), dim3(256), 0, stream,
                       dsqT, probT, partial);
    hipLaunchKernelGGL(bl_final,     dim3(1),    dim3(256), 0, stream,
                       partial, out);
}

// Round 11
// 26.034 us; speedup vs baseline: 1.1109x; 1.1109x over previous
//
#include <hip/hip_runtime.h>
#include <hip/hip_fp16.h>
#include <math.h>

typedef unsigned short u16;
typedef unsigned int   u32;
typedef u16 us2 __attribute__((ext_vector_type(2)));

constexpr int BB = 2, CC = 4, DD = 64, HH = 64, WW = 64;
constexpr int HW   = HH * WW;      // 4096
constexpr int DHW  = DD * HW;      // 262144
constexpr int CDHW = CC * DHW;     // 1048576
constexpr int NTOT = BB * CDHW;    // 2097152
constexpr int NBLK = 512;
constexpr u32 SENT = 50000;        // u16 "infinity": 50000+3969+3969 < 65536 (SWAR-safe)

__device__ __forceinline__ u32 pkmin(u32 a, u32 b) {
    us2 r = __builtin_elementwise_min(__builtin_bit_cast(us2, a),
                                      __builtin_bit_cast(us2, b));
    return __builtin_bit_cast(u32, r);
}
__device__ __forceinline__ float2 h2f(u32 w) {
    return __half22float2(__builtin_bit_cast(__half2, w));
}

// ---------------------------------------------------------------------------
// Kernel A: block = (b,c,d), 512 threads (R9-proven shape).
//  (1) W-pass: 8 waves x 8 rows, ballot nearest-set-bit -> u16 LDS.
//  (2) H-pass: packed-u16 min-plus, 1 row x 8 w per thread -> dsqT (u16).
//  (3) softmax probs (threads 0-255) -> probH[b][cc][h][d][w] as PACKED FP16.
// ---------------------------------------------------------------------------
__global__ __launch_bounds__(512) void edt_wh_prob(const int* __restrict__ tgt,
                                                   const float* __restrict__ pred,
                                                   u16* __restrict__ dsqT,
                                                   u16* __restrict__ probH) {
    __shared__ u16 fs[HW];   // 8 KB W-pass result [h][w]
    const int t    = threadIdx.x;
    const int blk  = blockIdx.x;
    const int lane = t & 63;
    const int wv   = t >> 6;           // 8 waves
    const int b = blk >> 8;
    const int c = (blk >> 6) & 3;
    const int d = blk & 63;
    const size_t tb = (size_t)(b * 64 + d) * HW;   // tgt[b][d][:][:]

    // W-pass: 8 rows per wave.
    #pragma unroll
    for (int r = 0; r < 8; ++r) {
        const int h   = wv * 8 + r;
        const int cls = tgt[tb + h * 64 + lane];
        const unsigned long long mask = __ballot(cls == c);
        const unsigned long long mlo  = mask & (~0ull >> (63 - lane));
        const unsigned long long mhi  = mask & (~0ull << lane);
        int dd = 1000;
        if (mlo) dd = lane - (63 - __builtin_clzll(mlo));
        if (mhi) dd = min(dd, (int)__builtin_ctzll(mhi) - lane);
        fs[h * 64 + lane] = (dd >= 1000) ? (u16)SENT : (u16)(dd * dd);
    }
    __syncthreads();

    // H-pass: packed u16 min-plus, 1 output row x 8 w per thread.
    const int i  = t >> 3;          // output row 0..63
    const int wg = (t & 7) * 8;     // 8 consecutive w
    u32 a0 = 0xFFFFFFFFu, a1 = 0xFFFFFFFFu, a2 = 0xFFFFFFFFu, a3 = 0xFFFFFFFFu;
    #pragma unroll 8
    for (int j = 0; j < 64; ++j) {
        const uint4 v = *reinterpret_cast<const uint4*>(&fs[j * 64 + wg]);
        const int  diff  = i - j;
        const u32  cost2 = (u32)(diff * diff) * 0x00010001u;  // SWAR pair
        a0 = pkmin(a0, v.x + cost2);
        a1 = pkmin(a1, v.y + cost2);
        a2 = pkmin(a2, v.z + cost2);
        a3 = pkmin(a3, v.w + cost2);
    }
    *reinterpret_cast<uint4*>(&dsqT[((size_t)(b * 4 + c) * 64 + i) * HW + d * 64 + wg])
        = make_uint4(a0, a1, a2, a3);

    // Softmax probs: quarter rows [16c,16c+16), threads 0-255, fp16 out.
    if (t < 256) {
        const int hh = c * 16 + (t >> 4);
        const int w0 = (t & 15) * 4;
        const size_t pidx = (size_t)b * CDHW + (size_t)d * HW + (size_t)hh * 64 + w0;
        const float4 q0 = *reinterpret_cast<const float4*>(&pred[pidx]);
        const float4 q1 = *reinterpret_cast<const float4*>(&pred[pidx + (size_t)DHW]);
        const float4 q2 = *reinterpret_cast<const float4*>(&pred[pidx + 2 * (size_t)DHW]);
        const float4 q3 = *reinterpret_cast<const float4*>(&pred[pidx + 3 * (size_t)DHW]);
        float4 o0, o1, o2, o3;
        #define SMAX(X)                                                          \
        {   const float m = fmaxf(fmaxf(q0.X, q1.X), fmaxf(q2.X, q3.X));         \
            const float e0 = __expf(q0.X - m), e1 = __expf(q1.X - m),            \
                        e2 = __expf(q2.X - m), e3 = __expf(q3.X - m);            \
            const float zinv = 1.0f / (e0 + e1 + e2 + e3);                       \
            o0.X = e0 * zinv; o1.X = e1 * zinv;                                  \
            o2.X = e2 * zinv; o3.X = e3 * zinv; }
        SMAX(x) SMAX(y) SMAX(z) SMAX(w)
        #undef SMAX
        const size_t ob = (size_t)b * CDHW + (size_t)hh * HW + d * 64 + w0;
        #define PSTORE(cc, o)                                                    \
        {   const u32 lo = __builtin_bit_cast(u32, __floats2half2_rn(o.x, o.y)); \
            const u32 hi = __builtin_bit_cast(u32, __floats2half2_rn(o.z, o.w)); \
            *reinterpret_cast<uint2*>(&probH[ob + (size_t)cc * DHW]) =           \
                make_uint2(lo, hi); }
        PSTORE(0, o0) PSTORE(1, o1) PSTORE(2, o2) PSTORE(3, o3)
        #undef PSTORE
    }
}

// ---------------------------------------------------------------------------
// Kernel B: block = (b,c,h) = blk, 512 threads (R9-proven shape). Stages the
// contiguous 8 KB u16 dsq slab, prefetches this thread's fp16 prob vector
// (one uint4 = 8 points), packed min-plus along d, fused prob*sqrt reduce.
// ---------------------------------------------------------------------------
__global__ __launch_bounds__(512) void edt_d_reduce(const u16* __restrict__ dsqT,
                                                    const u16* __restrict__ probH,
                                                    float* __restrict__ partial) {
    __shared__ u16   sdq[HW];   // 8 KB slab [d][w]
    __shared__ float wsum[8];
    const int t   = threadIdx.x;
    const int blk = blockIdx.x;
    const size_t base = (size_t)blk * HW;   // u16 units for both dsqT and probH

    const int i  = t >> 3;          // output d-row 0..63
    const int wg = (t & 7) * 8;

    // Issue both global loads back-to-back (one exposed latency).
    const uint4 s0 = reinterpret_cast<const uint4*>(&dsqT[base])[t];
    const uint4 pv = *reinterpret_cast<const uint4*>(&probH[base + i * 64 + wg]);
    reinterpret_cast<uint4*>(sdq)[t] = s0;
    __syncthreads();

    u32 a0 = 0xFFFFFFFFu, a1 = 0xFFFFFFFFu, a2 = 0xFFFFFFFFu, a3 = 0xFFFFFFFFu;
    #pragma unroll 8
    for (int j = 0; j < 64; ++j) {
        const uint4 v = *reinterpret_cast<const uint4*>(&sdq[j * 64 + wg]);
        const int  diff  = i - j;
        const u32  cost2 = (u32)(diff * diff) * 0x00010001u;
        a0 = pkmin(a0, v.x + cost2);
        a1 = pkmin(a1, v.y + cost2);
        a2 = pkmin(a2, v.z + cost2);
        a3 = pkmin(a3, v.w + cost2);
    }

    // Fused reduce: fp16 prob * sqrt(dsq), 8 points per thread.
    const float2 f0 = h2f(pv.x), f1 = h2f(pv.y), f2 = h2f(pv.z), f3 = h2f(pv.w);
    float vsum =
        f0.x * sqrtf((float)(a0 & 0xFFFFu)) + f0.y * sqrtf((float)(a0 >> 16)) +
        f1.x * sqrtf((float)(a1 & 0xFFFFu)) + f1.y * sqrtf((float)(a1 >> 16)) +
        f2.x * sqrtf((float)(a2 & 0xFFFFu)) + f2.y * sqrtf((float)(a2 >> 16)) +
        f3.x * sqrtf((float)(a3 & 0xFFFFu)) + f3.y * sqrtf((float)(a3 >> 16));

    const int lane = t & 63;
    #pragma unroll
    for (int off = 32; off > 0; off >>= 1) vsum += __shfl_down(vsum, off, 64);
    if (lane == 0) wsum[t >> 6] = vsum;
    __syncthreads();
    if (t == 0) {
        float s = 0.f;
        #pragma unroll
        for (int k = 0; k < 8; ++k) s += wsum[k];
        partial[blk] = s;
    }
}

// ---------------------------------------------------------------------------
// Kernel C: single-block deterministic final sum (proven tail).
// ---------------------------------------------------------------------------
__global__ __launch_bounds__(256) void bl_final(const float* __restrict__ partial,
                                                float* __restrict__ out) {
    __shared__ double sd[256];
    double s = (double)partial[threadIdx.x] + (double)partial[threadIdx.x + 256];
    sd[threadIdx.x] = s;
    __syncthreads();
    for (int str = 128; str > 0; str >>= 1) {
        if (threadIdx.x < str) sd[threadIdx.x] += sd[threadIdx.x + str];
        __syncthreads();
    }
    if (threadIdx.x == 0) out[0] = (float)(sd[0] / (double)NTOT);
}

// ---------------------------------------------------------------------------
extern "C" void kernel_launch(void* const* d_in, const int* in_sizes, int n_in,
                              void* d_out, int out_size, void* d_ws, size_t ws_size,
                              hipStream_t stream) {
    const float* pred = (const float*)d_in[0];
    const int*   tgt  = (const int*)d_in[1];
    float* out     = (float*)d_out;
    u16*   dsqT    = (u16*)d_ws;                          // NTOT u16 (4 MB)
    u16*   probH   = dsqT + NTOT;                         // NTOT u16 (4 MB)
    float* partial = (float*)(probH + NTOT);              // NBLK floats

    hipLaunchKernelGGL(edt_wh_prob,  dim3(NBLK), dim3(512), 0, stream,
                       tgt, pred, dsqT, probH);
    hipLaunchKernelGGL(edt_d_reduce, dim3(NBLK), dim3(512), 0, stream,
                       dsqT, probH, partial);
    hipLaunchKernelGGL(bl_final,     dim3(1),    dim3(256), 0, stream,
                       partial, out);
}

// Round 12
// 19.168 us; speedup vs baseline: 1.5088x; 1.3582x over previous
//
#include <hip/hip_runtime.h>
#include <hip/hip_fp16.h>
#include <math.h>

typedef unsigned short u16;
typedef unsigned int   u32;
typedef u16 us2 __attribute__((ext_vector_type(2)));

constexpr int BB = 2, CC = 4, DD = 64, HH = 64, WW = 64;
constexpr int HW   = HH * WW;      // 4096
constexpr int DHW  = DD * HW;      // 262144
constexpr int CDHW = CC * DHW;     // 1048576
constexpr int NTOT = BB * CDHW;    // 2097152
constexpr int NBLK = 512;
constexpr u32 SENT = 50000;        // u16 "infinity": 50000+2*3969 < 65536 (SWAR-safe)

__device__ __forceinline__ u32 pkmin(u32 a, u32 b) {
    us2 r = __builtin_elementwise_min(__builtin_bit_cast(us2, a),
                                      __builtin_bit_cast(us2, b));
    return __builtin_bit_cast(u32, r);
}
__device__ __forceinline__ u32 pkmax(u32 a, u32 b) {
    us2 r = __builtin_elementwise_max(__builtin_bit_cast(us2, a),
                                      __builtin_bit_cast(us2, b));
    return __builtin_bit_cast(u32, r);
}
__device__ __forceinline__ float2 h2f(u32 w) {
    return __half22float2(__builtin_bit_cast(__half2, w));
}

// Min-plus over rows of a [64][64] u16 LDS slab with outward early-exit:
// wave covers i in [I, I+7]; j scanned I..I+7 then expanding; exit when no
// remaining j can improve (f >= 0  =>  skip-safe iff (i-j)^2 >= max_w acc).
#define MINPLUS_SCAN(SRC)                                                      \
    u32 a0 = 0xFFFFFFFFu, a1 = 0xFFFFFFFFu, a2 = 0xFFFFFFFFu, a3 = 0xFFFFFFFFu;\
    {                                                                          \
        const int I = (t >> 6) * 8;                                            \
        _Pragma("unroll")                                                      \
        for (int k = 0; k < 8; ++k) {                                          \
            const int jj = I + k;                                              \
            const uint4 v = *reinterpret_cast<const uint4*>(&SRC[jj * 64 + wg]);\
            const int  df = i - jj;                                            \
            const u32  cst = (u32)(df * df) * 0x00010001u;                     \
            a0 = pkmin(a0, v.x + cst); a1 = pkmin(a1, v.y + cst);              \
            a2 = pkmin(a2, v.z + cst); a3 = pkmin(a3, v.w + cst);              \
        }                                                                      \
        int jlo = I - 1, jhi = I + 8;                                          \
        while (jlo >= 0 || jhi < 64) {                                         \
            const u32 pk  = pkmax(pkmax(a0, a1), pkmax(a2, a3));               \
            const u32 lo16 = pk & 0xFFFFu, hi16 = pk >> 16;                    \
            const u32 mm  = lo16 > hi16 ? lo16 : hi16;                         \
            const int dlo = (jlo >= 0) ? (i - jlo) : 1000;                     \
            const int dhi = (jhi < 64) ? (jhi - i) : 1000;                     \
            const int dm  = dlo < dhi ? dlo : dhi;                             \
            if (__all((u32)(dm * dm) >= mm)) break;                            \
            if (jlo >= 0) {                                                    \
                const uint4 v = *reinterpret_cast<const uint4*>(&SRC[jlo * 64 + wg]);\
                const int  df = i - jlo;                                       \
                const u32  cst = (u32)(df * df) * 0x00010001u;                 \
                a0 = pkmin(a0, v.x + cst); a1 = pkmin(a1, v.y + cst);          \
                a2 = pkmin(a2, v.z + cst); a3 = pkmin(a3, v.w + cst);          \
                --jlo;                                                         \
            }                                                                  \
            if (jhi < 64) {                                                    \
                const uint4 v = *reinterpret_cast<const uint4*>(&SRC[jhi * 64 + wg]);\
                const int  df = jhi - i;                                       \
                const u32  cst = (u32)(df * df) * 0x00010001u;                 \
                a0 = pkmin(a0, v.x + cst); a1 = pkmin(a1, v.y + cst);          \
                a2 = pkmin(a2, v.z + cst); a3 = pkmin(a3, v.w + cst);          \
                ++jhi;                                                         \
            }                                                                  \
        }                                                                      \
    }

// ---------------------------------------------------------------------------
// Kernel A: block = (b,c,d), 512 threads (R9/R11-proven shape).
//  (1) W-pass: 8 waves x 8 rows, ballot nearest-set-bit -> u16 LDS.
//  (2) H-pass: packed-u16 min-plus with early-exit -> dsqT[b][c][h][d][w].
//  (3) softmax probs (threads 0-255) -> probH (packed fp16, same layout).
// ---------------------------------------------------------------------------
__global__ __launch_bounds__(512) void edt_wh_prob(const int* __restrict__ tgt,
                                                   const float* __restrict__ pred,
                                                   u16* __restrict__ dsqT,
                                                   u16* __restrict__ probH) {
    __shared__ u16 fs[HW];   // 8 KB W-pass result [h][w]
    const int t    = threadIdx.x;
    const int blk  = blockIdx.x;
    const int lane = t & 63;
    const int wv   = t >> 6;           // 8 waves
    const int b = blk >> 8;
    const int c = (blk >> 6) & 3;
    const int d = blk & 63;
    const size_t tb = (size_t)(b * 64 + d) * HW;   // tgt[b][d][:][:]

    // W-pass: 8 rows per wave, ballot nearest-set-bit.
    #pragma unroll
    for (int r = 0; r < 8; ++r) {
        const int h   = wv * 8 + r;
        const int cls = tgt[tb + h * 64 + lane];
        const unsigned long long mask = __ballot(cls == c);
        const unsigned long long mlo  = mask & (~0ull >> (63 - lane));
        const unsigned long long mhi  = mask & (~0ull << lane);
        int dd = 1000;
        if (mlo) dd = lane - (63 - __builtin_clzll(mlo));
        if (mhi) dd = min(dd, (int)__builtin_ctzll(mhi) - lane);
        fs[h * 64 + lane] = (dd >= 1000) ? (u16)SENT : (u16)(dd * dd);
    }
    __syncthreads();

    // H-pass: 1 output row x 8 w per thread, early-exit scan.
    const int i  = t >> 3;          // output row 0..63
    const int wg = (t & 7) * 8;     // 8 consecutive w
    MINPLUS_SCAN(fs)
    *reinterpret_cast<uint4*>(&dsqT[((size_t)(b * 4 + c) * 64 + i) * HW + d * 64 + wg])
        = make_uint4(a0, a1, a2, a3);

    // Softmax probs: quarter rows [16c,16c+16), threads 0-255, fp16 out.
    if (t < 256) {
        const int hh = c * 16 + (t >> 4);
        const int w0 = (t & 15) * 4;
        const size_t pidx = (size_t)b * CDHW + (size_t)d * HW + (size_t)hh * 64 + w0;
        const float4 q0 = *reinterpret_cast<const float4*>(&pred[pidx]);
        const float4 q1 = *reinterpret_cast<const float4*>(&pred[pidx + (size_t)DHW]);
        const float4 q2 = *reinterpret_cast<const float4*>(&pred[pidx + 2 * (size_t)DHW]);
        const float4 q3 = *reinterpret_cast<const float4*>(&pred[pidx + 3 * (size_t)DHW]);
        float4 o0, o1, o2, o3;
        #define SMAX(X)                                                          \
        {   const float m = fmaxf(fmaxf(q0.X, q1.X), fmaxf(q2.X, q3.X));         \
            const float e0 = __expf(q0.X - m), e1 = __expf(q1.X - m),            \
                        e2 = __expf(q2.X - m), e3 = __expf(q3.X - m);            \
            const float zinv = 1.0f / (e0 + e1 + e2 + e3);                       \
            o0.X = e0 * zinv; o1.X = e1 * zinv;                                  \
            o2.X = e2 * zinv; o3.X = e3 * zinv; }
        SMAX(x) SMAX(y) SMAX(z) SMAX(w)
        #undef SMAX
        const size_t ob = (size_t)b * CDHW + (size_t)hh * HW + d * 64 + w0;
        #define PSTORE(cc, o)                                                    \
        {   const u32 lo = __builtin_bit_cast(u32, __floats2half2_rn(o.x, o.y)); \
            const u32 hi = __builtin_bit_cast(u32, __floats2half2_rn(o.z, o.w)); \
            *reinterpret_cast<uint2*>(&probH[ob + (size_t)cc * DHW]) =           \
                make_uint2(lo, hi); }
        PSTORE(0, o0) PSTORE(1, o1) PSTORE(2, o2) PSTORE(3, o3)
        #undef PSTORE
    }
}

// ---------------------------------------------------------------------------
// Kernel B: block = (b,c,h), 512 threads. Stages the contiguous 8 KB u16 dsq
// slab, prefetches the fp16 prob vector, early-exit min-plus along d, fused
// prob*sqrt reduce, partial store.
// ---------------------------------------------------------------------------
__global__ __launch_bounds__(512) void edt_d_reduce(const u16* __restrict__ dsqT,
                                                    const u16* __restrict__ probH,
                                                    float* __restrict__ partial) {
    __shared__ u16   sdq[HW];   // 8 KB slab [d][w]
    __shared__ float wsum[8];
    const int t   = threadIdx.x;
    const int blk = blockIdx.x;
    const size_t base = (size_t)blk * HW;   // u16 units for both dsqT and probH

    const int i  = t >> 3;          // output d-row 0..63
    const int wg = (t & 7) * 8;

    // Issue both global loads back-to-back (one exposed latency).
    const uint4 s0 = reinterpret_cast<const uint4*>(&dsqT[base])[t];
    const uint4 pv = *reinterpret_cast<const uint4*>(&probH[base + i * 64 + wg]);
    reinterpret_cast<uint4*>(sdq)[t] = s0;
    __syncthreads();

    MINPLUS_SCAN(sdq)

    // Fused reduce: fp16 prob * sqrt(dsq), 8 points per thread.
    const float2 f0 = h2f(pv.x), f1 = h2f(pv.y), f2 = h2f(pv.z), f3 = h2f(pv.w);
    float vsum =
        f0.x * sqrtf((float)(a0 & 0xFFFFu)) + f0.y * sqrtf((float)(a0 >> 16)) +
        f1.x * sqrtf((float)(a1 & 0xFFFFu)) + f1.y * sqrtf((float)(a1 >> 16)) +
        f2.x * sqrtf((float)(a2 & 0xFFFFu)) + f2.y * sqrtf((float)(a2 >> 16)) +
        f3.x * sqrtf((float)(a3 & 0xFFFFu)) + f3.y * sqrtf((float)(a3 >> 16));

    const int lane = t & 63;
    #pragma unroll
    for (int off = 32; off > 0; off >>= 1) vsum += __shfl_down(vsum, off, 64);
    if (lane == 0) wsum[t >> 6] = vsum;
    __syncthreads();
    if (t == 0) {
        float s = 0.f;
        #pragma unroll
        for (int k = 0; k < 8; ++k) s += wsum[k];
        partial[blk] = s;
    }
}

// ---------------------------------------------------------------------------
// Kernel C: single-block deterministic final sum (proven tail).
// ---------------------------------------------------------------------------
__global__ __launch_bounds__(256) void bl_final(const float* __restrict__ partial,
                                                float* __restrict__ out) {
    __shared__ double sd[256];
    double s = (double)partial[threadIdx.x] + (double)partial[threadIdx.x + 256];
    sd[threadIdx.x] = s;
    __syncthreads();
    for (int str = 128; str > 0; str >>= 1) {
        if (threadIdx.x < str) sd[threadIdx.x] += sd[threadIdx.x + str];
        __syncthreads();
    }
    if (threadIdx.x == 0) out[0] = (float)(sd[0] / (double)NTOT);
}

// ---------------------------------------------------------------------------
extern "C" void kernel_launch(void* const* d_in, const int* in_sizes, int n_in,
                              void* d_out, int out_size, void* d_ws, size_t ws_size,
                              hipStream_t stream) {
    const float* pred = (const float*)d_in[0];
    const int*   tgt  = (const int*)d_in[1];
    float* out     = (float*)d_out;
    u16*   dsqT    = (u16*)d_ws;                          // NTOT u16 (4 MB)
    u16*   probH   = dsqT + NTOT;                         // NTOT u16 (4 MB)
    float* partial = (float*)(probH + NTOT);              // NBLK floats

    hipLaunchKernelGGL(edt_wh_prob,  dim3(NBLK), dim3(512), 0, stream,
                       tgt, pred, dsqT, probH);
    hipLaunchKernelGGL(edt_d_reduce, dim3(NBLK), dim3(512), 0, stream,
                       dsqT, probH, partial);
    hipLaunchKernelGGL(bl_final,     dim3(1),    dim3(256), 0, stream,
                       partial, out);
}